// Round 1
// baseline (10582.338 us; speedup 1.0000x reference)
//
#include <hip/hip_runtime.h>

// SpMM edge-list baseline:
//   out[row[e], :] += in_norm[row[e]] * out_norm[col[e]] * values[e] * x[col[e], :]
// One 64-lane wave per edge; each lane handles 4 consecutive floats (float4).

__global__ void zero_out_kernel(float4* out, int n4) {
    int i = blockIdx.x * blockDim.x + threadIdx.x;
    int stride = gridDim.x * blockDim.x;
    for (; i < n4; i += stride) out[i] = make_float4(0.f, 0.f, 0.f, 0.f);
}

__global__ __launch_bounds__(256) void edge_scatter_kernel(
    const float* __restrict__ x,
    const int* __restrict__ row,
    const int* __restrict__ col,
    const float* __restrict__ values,
    const float* __restrict__ out_norm,
    const float* __restrict__ in_norm,
    float* __restrict__ out,
    int E, int D)
{
    // 4 waves per 256-thread block, one edge per wave
    int wave_in_block = threadIdx.x >> 6;
    int lane = threadIdx.x & 63;
    int e = blockIdx.x * 4 + wave_in_block;
    if (e >= E) return;

    int r = row[e];
    int c = col[e];
    float s = values[e] * out_norm[c] * in_norm[r];

    const float4* xs = reinterpret_cast<const float4*>(x + (size_t)c * D);
    float4 v = xs[lane];                       // coalesced: 64 lanes x 16B = 1KB row

    float* o = out + (size_t)r * D + lane * 4;
    atomicAdd(o + 0, v.x * s);
    atomicAdd(o + 1, v.y * s);
    atomicAdd(o + 2, v.z * s);
    atomicAdd(o + 3, v.w * s);
}

extern "C" void kernel_launch(void* const* d_in, const int* in_sizes, int n_in,
                              void* d_out, int out_size, void* d_ws, size_t ws_size,
                              hipStream_t stream) {
    const float* x        = (const float*)d_in[0];
    const int*   row      = (const int*)  d_in[1];
    const int*   col      = (const int*)  d_in[2];
    const float* values   = (const float*)d_in[3];
    const float* out_norm = (const float*)d_in[4];
    const float* in_norm  = (const float*)d_in[5];
    float* out = (float*)d_out;

    const int E = in_sizes[1];          // edges
    const int N = in_sizes[4];          // nodes (out_norm has N elements)
    const int D = in_sizes[0] / N;      // feature dim (256)

    // 1) zero the accumulator (d_out is poisoned before timing)
    int n4 = (N * D) / 4;
    zero_out_kernel<<<2048, 256, 0, stream>>>((float4*)out, n4);

    // 2) scatter-add all edges, one wave per edge
    int blocks = (E + 3) / 4;
    edge_scatter_kernel<<<blocks, 256, 0, stream>>>(
        x, row, col, values, out_norm, in_norm, out, E, D);
}

// Round 2
// 739.801 us; speedup vs baseline: 14.3043x; 14.3043x over previous
//
#include <hip/hip_runtime.h>

// SpMM via on-device CSR build + register-accumulating gather.
// out[r,:] = in_norm[r] * sum_{e: row[e]==r} (values[e]*out_norm[col[e]]) * x[col[e],:]
//
// Pipeline (all per-call, deterministic):
//  1) zero counts+cursor
//  2) histogram rows
//  3) hierarchical exclusive scan -> row_ptr
//  4) bucket-fill (col, scaled val) pairs into ws
//  5) gather: 1 wave per output row, accumulate in regs, single write

#define WAVE 64

// ---------------- fallback (atomic scatter) ----------------
__global__ void zero_out_kernel(float4* out, int n4) {
    int i = blockIdx.x * blockDim.x + threadIdx.x;
    int stride = gridDim.x * blockDim.x;
    for (; i < n4; i += stride) out[i] = make_float4(0.f, 0.f, 0.f, 0.f);
}

__global__ __launch_bounds__(256) void edge_scatter_kernel(
    const float* __restrict__ x, const int* __restrict__ row,
    const int* __restrict__ col, const float* __restrict__ values,
    const float* __restrict__ out_norm, const float* __restrict__ in_norm,
    float* __restrict__ out, int E, int D)
{
    int wave_in_block = threadIdx.x >> 6;
    int lane = threadIdx.x & 63;
    int e = blockIdx.x * 4 + wave_in_block;
    if (e >= E) return;
    int r = row[e], c = col[e];
    float s = values[e] * out_norm[c] * in_norm[r];
    const float4* xs = reinterpret_cast<const float4*>(x + (size_t)c * D);
    float4 v = xs[lane];
    float* o = out + (size_t)r * D + lane * 4;
    atomicAdd(o + 0, v.x * s);
    atomicAdd(o + 1, v.y * s);
    atomicAdd(o + 2, v.z * s);
    atomicAdd(o + 3, v.w * s);
}

// ---------------- CSR build ----------------
__global__ void zero_ints_kernel(int* p, int n) {
    int i = blockIdx.x * blockDim.x + threadIdx.x;
    int stride = gridDim.x * blockDim.x;
    for (; i < n; i += stride) p[i] = 0;
}

__global__ __launch_bounds__(256) void hist_kernel(
    const int* __restrict__ row, int* __restrict__ counts, int E)
{
    int i = blockIdx.x * blockDim.x + threadIdx.x;
    int stride = gridDim.x * blockDim.x;
    for (; i < E; i += stride) atomicAdd(&counts[row[i]], 1);
}

// per-block (1024 items) sums
__global__ __launch_bounds__(256) void block_sum_kernel(
    const int* __restrict__ counts, int* __restrict__ partials, int N)
{
    int base = blockIdx.x * 1024;
    int tid = threadIdx.x;
    int s = 0;
    int idx = base + tid * 4;
    #pragma unroll
    for (int k = 0; k < 4; ++k) { int i = idx + k; if (i < N) s += counts[i]; }
    #pragma unroll
    for (int d = 32; d >= 1; d >>= 1) s += __shfl_down(s, d);
    __shared__ int wsum[4];
    int lane = tid & 63, wid = tid >> 6;
    if (lane == 0) wsum[wid] = s;
    __syncthreads();
    if (tid == 0) partials[blockIdx.x] = wsum[0] + wsum[1] + wsum[2] + wsum[3];
}

// tiny serial exclusive scan of block partials (nb ~ 98)
__global__ void scan_partials_kernel(int* partials, int nb) {
    if (blockIdx.x == 0 && threadIdx.x == 0) {
        int sum = 0;
        for (int b = 0; b < nb; ++b) { int t = partials[b]; partials[b] = sum; sum += t; }
    }
}

// per-block exclusive scan using wave shfl + LDS; writes inclusive into row_ptr[i+1]
__global__ __launch_bounds__(256) void scan_block_kernel(
    const int* __restrict__ counts, const int* __restrict__ partials,
    int* __restrict__ row_ptr, int N)
{
    int b = blockIdx.x;
    int base = b * 1024;
    int tid = threadIdx.x;
    int lane = tid & 63, wid = tid >> 6;
    int idx = base + tid * 4;

    int c0 = (idx + 0 < N) ? counts[idx + 0] : 0;
    int c1 = (idx + 1 < N) ? counts[idx + 1] : 0;
    int c2 = (idx + 2 < N) ? counts[idx + 2] : 0;
    int c3 = (idx + 3 < N) ? counts[idx + 3] : 0;
    int i0 = c0, i1 = i0 + c1, i2 = i1 + c2, i3 = i2 + c3;

    // inclusive wave scan of per-thread totals
    int s = i3;
    #pragma unroll
    for (int d = 1; d < 64; d <<= 1) {
        int t = __shfl_up(s, d);
        if (lane >= d) s += t;
    }
    int excl = s - i3;

    __shared__ int wsum[4];
    if (lane == 63) wsum[wid] = s;
    __syncthreads();
    int woff = 0;
    for (int w = 0; w < wid; ++w) woff += wsum[w];

    int off = partials[b] + woff + excl;
    if (idx + 0 < N) row_ptr[idx + 1] = off + i0;
    if (idx + 1 < N) row_ptr[idx + 2] = off + i1;
    if (idx + 2 < N) row_ptr[idx + 3] = off + i2;
    if (idx + 3 < N) row_ptr[idx + 4] = off + i3;
    if (b == 0 && tid == 0) row_ptr[0] = 0;
}

// bucket-fill: pairs[pos] = (col, values[e]*out_norm[col])
__global__ __launch_bounds__(256) void fill_kernel(
    const int* __restrict__ row, const int* __restrict__ col,
    const float* __restrict__ values, const float* __restrict__ out_norm,
    const int* __restrict__ row_ptr, int* __restrict__ cursor,
    int2* __restrict__ pairs, int E)
{
    int i = blockIdx.x * blockDim.x + threadIdx.x;
    int stride = gridDim.x * blockDim.x;
    for (; i < E; i += stride) {
        int r = row[i], c = col[i];
        float v = values[i] * out_norm[c];
        int pos = row_ptr[r] + atomicAdd(&cursor[r], 1);
        pairs[pos] = make_int2(c, __float_as_int(v));
    }
}

// gather: 1 wave per row, lane owns float4 slice; single coalesced write
__global__ __launch_bounds__(256) void gather_kernel(
    const float* __restrict__ x, const int2* __restrict__ pairs,
    const int* __restrict__ row_ptr, const float* __restrict__ in_norm,
    float* __restrict__ out, int N, int D)
{
    int wid = threadIdx.x >> 6;
    int lane = threadIdx.x & 63;
    int r = blockIdx.x * 4 + wid;
    if (r >= N) return;

    int beg = row_ptr[r], end = row_ptr[r + 1];
    float4 acc = make_float4(0.f, 0.f, 0.f, 0.f);
    const float4* xb = reinterpret_cast<const float4*>(x);

    for (int j = beg; j < end; ++j) {
        int2 p = pairs[j];                       // wave-uniform addr -> broadcast
        float v = __int_as_float(p.y);
        float4 xv = xb[(size_t)p.x * (D / 4) + lane];
        acc.x += v * xv.x;
        acc.y += v * xv.y;
        acc.z += v * xv.z;
        acc.w += v * xv.w;
    }

    float sc = in_norm[r];
    float4* ob = reinterpret_cast<float4*>(out);
    float4 o;
    o.x = acc.x * sc; o.y = acc.y * sc; o.z = acc.z * sc; o.w = acc.w * sc;
    ob[(size_t)r * (D / 4) + lane] = o;
}

extern "C" void kernel_launch(void* const* d_in, const int* in_sizes, int n_in,
                              void* d_out, int out_size, void* d_ws, size_t ws_size,
                              hipStream_t stream) {
    const float* x        = (const float*)d_in[0];
    const int*   row      = (const int*)  d_in[1];
    const int*   col      = (const int*)  d_in[2];
    const float* values   = (const float*)d_in[3];
    const float* out_norm = (const float*)d_in[4];
    const float* in_norm  = (const float*)d_in[5];
    float* out = (float*)d_out;

    const int E = in_sizes[1];
    const int N = in_sizes[4];
    const int D = in_sizes[0] / N;   // 256

    const int nb = (N + 1023) / 1024;

    // ws layout (ints): counts[N] | cursor[N] | row_ptr[N+1] | partials[nb] | pad | pairs[E] (int2)
    size_t hdr_ints = (size_t)N + N + (N + 1) + nb;
    hdr_ints = (hdr_ints + 1) & ~(size_t)1;          // 8B-align pairs
    size_t need = hdr_ints * 4 + (size_t)E * 8;

    if (ws_size < need || (D % 4) != 0) {
        // fallback: atomic scatter
        int n4 = (N * D) / 4;
        zero_out_kernel<<<2048, 256, 0, stream>>>((float4*)out, n4);
        int blocks = (E + 3) / 4;
        edge_scatter_kernel<<<blocks, 256, 0, stream>>>(
            x, row, col, values, out_norm, in_norm, out, E, D);
        return;
    }

    int* counts   = (int*)d_ws;
    int* cursor   = counts + N;
    int* row_ptr  = cursor + N;
    int* partials = row_ptr + N + 1;
    int2* pairs   = (int2*)((int*)d_ws + hdr_ints);

    // 1) zero counts + cursor (contiguous 2N ints)
    zero_ints_kernel<<<1024, 256, 0, stream>>>(counts, 2 * N);
    // 2) histogram
    hist_kernel<<<2048, 256, 0, stream>>>(row, counts, E);
    // 3) scan -> row_ptr
    block_sum_kernel<<<nb, 256, 0, stream>>>(counts, partials, N);
    scan_partials_kernel<<<1, 64, 0, stream>>>(partials, nb);
    scan_block_kernel<<<nb, 256, 0, stream>>>(counts, partials, row_ptr, N);
    // 4) bucket fill
    fill_kernel<<<2048, 256, 0, stream>>>(row, col, values, out_norm,
                                          row_ptr, cursor, pairs, E);
    // 5) gather
    gather_kernel<<<(N + 3) / 4, 256, 0, stream>>>(x, pairs, row_ptr, in_norm,
                                                   out, N, D);
}